// Round 6
// baseline (2732.443 us; speedup 1.0000x reference)
//
#include <hip/hip_runtime.h>
#include <hip/hip_bf16.h>
#include <cstdint>

// GRU scan: T=256, B=64, H=1024.
// gi = x@Wi + bi precomputed with one bf16 MFMA GEMM; then a persistent
// 256-WG x 256-thread kernel walks 256 sequential steps.
// NEW: 8 groups of 8 batches, one group per XCD (g = wg&7 under round-robin
// dispatch). h exchange is sentinel-in-data (0xFF... = -NaN bf16 words) via
// the XCD's own L2: producers double-store (plain -> local L2, sc0 sc1 ->
// MALL mirror); consumers spin sc0 loads and stickily escalate to sc0 sc1
// after bounded failures, so correctness never depends on placement.
// Wh is held ENTIRELY in registers (48 B-frags/wave = 192 VGPR, M=8 tiles);
// no LDS staging in the loop. Reduce/epilogue/publish split across 4 waves.

#define TT 256
#define BB 64
#define HH 1024
#define H3 3072

typedef __attribute__((ext_vector_type(8))) short s16x8;
typedef __attribute__((ext_vector_type(4))) float f32x4;
typedef __attribute__((ext_vector_type(4))) unsigned int u32x4;
typedef unsigned long long ull;

__device__ __forceinline__ float fast_sigmoid(float x) {
  float e = __expf(-fabsf(x));
  float s = 1.0f / (1.0f + e);
  return x >= 0.0f ? s : 1.0f - s;
}
__device__ __forceinline__ float fast_tanh(float x) {
  float e = __expf(-2.0f * fabsf(x));
  float t = (1.0f - e) / (1.0f + e);
  return x >= 0.0f ? t : -t;
}
__device__ __forceinline__ f32x4 mfma16(s16x8 a, s16x8 b, f32x4 c) {
  return __builtin_amdgcn_mfma_f32_16x16x32_bf16(a, b, c, 0, 0, 0);
}

// ---------------- poll/publish primitives ----------------

// 16B load, L2-coherent (sc0) or MALL-coherent (sc0 sc1); data valid at return
__device__ __forceinline__ u32x4 ld16c(const char* p, bool e) {
  u32x4 r;
  if (!e)
    asm volatile("global_load_dwordx4 %0, %1, off sc0\n\t"
                 "s_waitcnt vmcnt(0)"
                 : "=&v"(r) : "v"(p) : "memory");
  else
    asm volatile("global_load_dwordx4 %0, %1, off sc0 sc1\n\t"
                 "s_waitcnt vmcnt(0)"
                 : "=&v"(r) : "v"(p) : "memory");
  return r;
}

// 8 x 16B chunk load (offsets 0..448), single waitcnt
__device__ __forceinline__ void ld8_sc0(u32x4 (&W)[8], const char* b) {
  asm volatile(
      "global_load_dwordx4 %0, %8, off sc0\n\t"
      "global_load_dwordx4 %1, %8, off offset:64 sc0\n\t"
      "global_load_dwordx4 %2, %8, off offset:128 sc0\n\t"
      "global_load_dwordx4 %3, %8, off offset:192 sc0\n\t"
      "global_load_dwordx4 %4, %8, off offset:256 sc0\n\t"
      "global_load_dwordx4 %5, %8, off offset:320 sc0\n\t"
      "global_load_dwordx4 %6, %8, off offset:384 sc0\n\t"
      "global_load_dwordx4 %7, %8, off offset:448 sc0\n\t"
      "s_waitcnt vmcnt(0)"
      : "=&v"(W[0]), "=&v"(W[1]), "=&v"(W[2]), "=&v"(W[3]),
        "=&v"(W[4]), "=&v"(W[5]), "=&v"(W[6]), "=&v"(W[7])
      : "v"(b) : "memory");
}
__device__ __forceinline__ void ld8_sc1(u32x4 (&W)[8], const char* b) {
  asm volatile(
      "global_load_dwordx4 %0, %8, off sc0 sc1\n\t"
      "global_load_dwordx4 %1, %8, off offset:64 sc0 sc1\n\t"
      "global_load_dwordx4 %2, %8, off offset:128 sc0 sc1\n\t"
      "global_load_dwordx4 %3, %8, off offset:192 sc0 sc1\n\t"
      "global_load_dwordx4 %4, %8, off offset:256 sc0 sc1\n\t"
      "global_load_dwordx4 %5, %8, off offset:320 sc0 sc1\n\t"
      "global_load_dwordx4 %6, %8, off offset:384 sc0 sc1\n\t"
      "global_load_dwordx4 %7, %8, off offset:448 sc0 sc1\n\t"
      "s_waitcnt vmcnt(0)"
      : "=&v"(W[0]), "=&v"(W[1]), "=&v"(W[2]), "=&v"(W[3]),
        "=&v"(W[4]), "=&v"(W[5]), "=&v"(W[6]), "=&v"(W[7])
      : "v"(b) : "memory");
}

// publish 8B: plain (local L2, fast path) + sc0 sc1 mirror (MALL, fallback)
__device__ __forceinline__ void st8_pub(char* p, ull v) {
  asm volatile("global_store_dwordx2 %0, %1, off\n\t"
               "global_store_dwordx2 %0, %1, off sc0 sc1"
               :: "v"(p), "v"(v) : "memory");
}

// word-sentinel test: an 8B h word is 0xFFFF.. iff unwritten
__device__ __forceinline__ unsigned sentq(const u32x4& v) {
  return (unsigned)(((v[0] & v[1]) == ~0u) | ((v[2] & v[3]) == ~0u));
}

// ---------------- setup kernels ----------------

__global__ void k_cvt_x(const float* __restrict__ x, __hip_bfloat16* __restrict__ xb, int n) {
  int i = (blockIdx.x * blockDim.x + threadIdx.x) * 4;
  if (i + 3 < n) {
    float4 v = *reinterpret_cast<const float4*>(x + i);
    xb[i + 0] = __float2bfloat16(v.x);
    xb[i + 1] = __float2bfloat16(v.y);
    xb[i + 2] = __float2bfloat16(v.z);
    xb[i + 3] = __float2bfloat16(v.w);
  }
}

// W [1024][3072] f32 -> WT [3072][1024] bf16
__global__ void k_transpose_w(const float* __restrict__ W, __hip_bfloat16* __restrict__ WT) {
  __shared__ float tile[32][33];
  int c0 = blockIdx.x * 32, r0 = blockIdx.y * 32;
  int tx = threadIdx.x & 31, ty = threadIdx.x >> 5;  // 256 threads: 32x8
#pragma unroll
  for (int i = 0; i < 32; i += 8)
    tile[ty + i][tx] = W[(size_t)(r0 + ty + i) * H3 + c0 + tx];
  __syncthreads();
#pragma unroll
  for (int i = 0; i < 32; i += 8)
    WT[(size_t)(c0 + ty + i) * HH + r0 + tx] = __float2bfloat16(tile[tx][ty + i]);
}

// sentinel fill via agent-scope stores (NO plain dirty lines in random L2s)
__global__ void k_fill_sentinel(ull* __restrict__ p, int nwords) {
  int idx = blockIdx.x * blockDim.x + threadIdx.x;
  for (int i = idx; i < nwords; i += gridDim.x * blockDim.x)
    __hip_atomic_store(p + i, ~0ull, __ATOMIC_RELAXED, __HIP_MEMORY_SCOPE_AGENT);
}

// ---------------- gi = x @ Wi + bi  (bf16 MFMA, 128x128 tile, BK=32) ----------------

template <bool GIF32>
__global__ __launch_bounds__(256, 2) void k_gemm_gi(
    const __hip_bfloat16* __restrict__ A,   // [16384][1024] x bf16
    const __hip_bfloat16* __restrict__ Bt,  // [3072][1024]  Wi^T bf16
    const float* __restrict__ bi,           // [3072]
    void* __restrict__ gi)                  // [16384][3072] f32 or bf16
{
  __shared__ __align__(16) __hip_bfloat16 As[128 * 32];
  __shared__ __align__(16) __hip_bfloat16 Bs[128 * 32];
  const int bid = blockIdx.x;
  const int mt = bid / 24, nt = bid % 24;
  const int m0 = mt * 128, n0 = nt * 128;
  const int tid = threadIdx.x, lane = tid & 63, w = tid >> 6;
  const int wm = w & 1, wn = w >> 1;

  f32x4 acc[4][4];
#pragma unroll
  for (int ai = 0; ai < 4; ++ai)
#pragma unroll
    for (int bj = 0; bj < 4; ++bj) acc[ai][bj] = (f32x4){0.f, 0.f, 0.f, 0.f};

  for (int k0 = 0; k0 < HH; k0 += 32) {
#pragma unroll
    for (int i = 0; i < 2; ++i) {
      const int c = w + i * 4;
      const int idx = c * 64 + lane;
      const int row = idx >> 2, slot = idx & 3;
      __builtin_amdgcn_global_load_lds(
          (const __attribute__((address_space(1))) void*)(A + (size_t)(m0 + row) * HH + k0 + slot * 8),
          (__attribute__((address_space(3))) void*)(As + c * 512), 16, 0, 0);
      __builtin_amdgcn_global_load_lds(
          (const __attribute__((address_space(1))) void*)(Bt + (size_t)(n0 + row) * HH + k0 + slot * 8),
          (__attribute__((address_space(3))) void*)(Bs + c * 512), 16, 0, 0);
    }
    __syncthreads();
    s16x8 af[4], bf[4];
#pragma unroll
    for (int ai = 0; ai < 4; ++ai) {
      int r = wm * 64 + ai * 16 + (lane & 15);
      af[ai] = *reinterpret_cast<const s16x8*>(As + r * 32 + (lane >> 4) * 8);
    }
#pragma unroll
    for (int bj = 0; bj < 4; ++bj) {
      int r = wn * 64 + bj * 16 + (lane & 15);
      bf[bj] = *reinterpret_cast<const s16x8*>(Bs + r * 32 + (lane >> 4) * 8);
    }
#pragma unroll
    for (int ai = 0; ai < 4; ++ai)
#pragma unroll
      for (int bj = 0; bj < 4; ++bj) acc[ai][bj] = mfma16(af[ai], bf[bj], acc[ai][bj]);
    __syncthreads();
  }

#pragma unroll
  for (int ai = 0; ai < 4; ++ai) {
#pragma unroll
    for (int reg = 0; reg < 4; ++reg) {
      const size_t row = (size_t)m0 + wm * 64 + ai * 16 + (lane >> 4) * 4 + reg;
#pragma unroll
      for (int bj = 0; bj < 4; ++bj) {
        const int col = n0 + wn * 64 + bj * 16 + (lane & 15);
        float v = acc[ai][bj][reg] + bi[col];
        if (GIF32)
          reinterpret_cast<float*>(gi)[row * H3 + col] = v;
        else
          reinterpret_cast<__hip_bfloat16*>(gi)[row * H3 + col] = __float2bfloat16(v);
      }
    }
  }
}

// ---------------- persistent step kernel ----------------

// 256 WGs x 256 threads. Group g = wg&7 (one per XCD): batches [8g,8g+8).
// WG s = wg>>3: j-cols [32s,32s+32). Wave w: K-chunk [256w,256w+256) for the
// MFMA phase; epilogue cols [j0+8w, j0+8w+8).
template <bool GIF32>
__global__ __launch_bounds__(256, 1) void k_gru(
    const void* __restrict__ gi_,
    const int* __restrict__ resets,   // [256][64]
    const float* __restrict__ h0,     // [64][1024]
    const float* __restrict__ bn,     // [1024]
    const __hip_bfloat16* __restrict__ WhT,  // [3072][1024]
    __hip_bfloat16* hseq,                    // [257][64][1024] sentinel-filled
    float* __restrict__ out)                 // [64*1024 hfinal | 256*64*1024 ys]
{
  __shared__ __align__(16) f32x4 part[2][4][6][32];      // 24 KB partials
  __shared__ __align__(8) __hip_bfloat16 hshW[4][8][8];  // 512 B transpose

  const int tid = threadIdx.x;
  const int wave = tid >> 6, lane = tid & 63;
  const int wg = blockIdx.x;
  const int g = wg & 7;        // target: physical XCD (perf heuristic only)
  const int s = wg >> 3;       // 0..31
  const int bg0 = g * 8, j0 = s * 32;
  const int lq = lane >> 4, lc = lane & 15;

  // ---- Wh fragments for this wave's K-chunk: ALL in registers ----
  // tile = gate*2+nt (gate 0=r,1=z,2=n; nt col-halves); frag(tile,kk):
  // B[col = j0+nt*16+lc][k = wave*256 + kk*32 + lq*8 .. +8)
  s16x8 bf[6][8];
#pragma unroll
  for (int gate = 0; gate < 3; ++gate)
#pragma unroll
    for (int nt = 0; nt < 2; ++nt)
#pragma unroll
      for (int kk = 0; kk < 8; ++kk)
        bf[gate * 2 + nt][kk] = *reinterpret_cast<const s16x8*>(
            WhT + (size_t)(gate * HH + j0 + nt * 16 + lc) * HH + wave * 256 + kk * 32 + lq * 8);

  // ---- epilogue state (lanes 0..15 of each wave) ----
  const int colg = j0 + 8 * wave + (lane & 7);       // this lane's j column
  const int brow0 = bg0 + ((lane >> 3) & 1) * 4;     // rows brow0..brow0+3
  float hp[4], giR[4], giZ[4], giN[4];
  int rstE[4];
  float bnj = 0.f;
  char* const hseqB = reinterpret_cast<char*>(hseq);

  if (lane < 16) {
    bnj = bn[colg];
#pragma unroll
    for (int i = 0; i < 4; ++i) {
      const int b = brow0 + i;
      hp[i] = h0[(size_t)b * HH + colg];
      rstE[i] = resets[b];
      if (GIF32) {
        const float* grow = reinterpret_cast<const float*>(gi_) + (size_t)b * H3;
        giR[i] = grow[colg]; giZ[i] = grow[HH + colg]; giN[i] = grow[2 * HH + colg];
      } else {
        const __hip_bfloat16* grow =
            reinterpret_cast<const __hip_bfloat16*>(gi_) + (size_t)b * H3;
        giR[i] = __bfloat162float(grow[colg]);
        giZ[i] = __bfloat162float(grow[HH + colg]);
        giN[i] = __bfloat162float(grow[2 * HH + colg]);
      }
      hshW[wave][(b - bg0)][lane & 7] = __float2bfloat16(hp[i]);
    }
    // publish slot 0 (h_{-1}): 16 lanes x 8B, plain + MALL mirror
    ull pv = *reinterpret_cast<const ull*>(&hshW[wave][lane >> 1][(lane & 1) * 4]);
    st8_pub(hseqB + ((size_t)(bg0 + (lane >> 1)) * HH + j0 + 8 * wave + (lane & 1) * 4) * 2, pv);
  }

  // ---- per-lane poll geometry: row = bg0 + (lane&7), k-chunk of this wave ----
  const size_t abyte = ((size_t)(bg0 + (lane & 7)) * HH + wave * 256 + lq * 8) * 2;
  bool esc = false;  // sticky escalation to MALL-coherent loads

  for (int t = 0; t < TT; ++t) {
    const int p = t & 1;
    const int rstA = resets[t * BB + bg0 + (lane & 7)];
    const char* cb = hseqB + (size_t)t * 131072 + abyte;

    // canary spin: last 16B frag of my chunk
    {
      int it = 0;
      for (;;) {
        u32x4 c = ld16c(cb + 448, esc);
        if (!__any((int)sentq(c))) break;
        if (++it == 1024) esc = true;
        if (it > (1 << 21)) break;
      }
    }
    // full chunk + verify (stragglers from other producer WGs)
    u32x4 w[8];
    if (!esc) ld8_sc0(w, cb); else ld8_sc1(w, cb);
    {
      int vt = 0;
      for (;;) {
        unsigned bad = 0;
#pragma unroll
        for (int i = 0; i < 8; ++i) bad |= sentq(w[i]);
        if (!__any((int)bad)) break;
        if (++vt == 256) esc = true;
        if (vt > (1 << 19)) break;
        if (!esc) ld8_sc0(w, cb); else ld8_sc1(w, cb);
      }
    }

    // 48 register-only MFMAs (M=8: lanes lc>=8 and reset rows feed zeros)
    const unsigned vm = (lc < 8 && !rstA) ? ~0u : 0u;
    f32x4 acc[6];
#pragma unroll
    for (int tl = 0; tl < 6; ++tl) acc[tl] = (f32x4){0.f, 0.f, 0.f, 0.f};
#pragma unroll
    for (int kk = 0; kk < 8; ++kk) {
      u32x4 m = w[kk];
      m[0] &= vm; m[1] &= vm; m[2] &= vm; m[3] &= vm;
      s16x8 a = __builtin_bit_cast(s16x8, m);
#pragma unroll
      for (int tl = 0; tl < 6; ++tl) acc[tl] = mfma16(a, bf[tl][kk], acc[tl]);
    }

    if (lane < 32) {
#pragma unroll
      for (int tl = 0; tl < 6; ++tl) part[p][wave][tl][lane] = acc[tl];
    }
    __syncthreads();

    if (lane < 16) {
      // reduce my col-slice: tiles {ntE, 2+ntE, 4+ntE} at element pi
      const int ntE = wave >> 1;
      const int pi = ((lane >> 3) << 4) | ((wave & 1) << 3) | (lane & 7);
      f32x4 sR = part[p][0][ntE][pi];
      f32x4 sZ = part[p][0][2 + ntE][pi];
      f32x4 sN = part[p][0][4 + ntE][pi];
#pragma unroll
      for (int ww = 1; ww < 4; ++ww) {
        sR += part[p][ww][ntE][pi];
        sZ += part[p][ww][2 + ntE][pi];
        sN += part[p][ww][4 + ntE][pi];
      }
      float hnew[4];
#pragma unroll
      for (int i = 0; i < 4; ++i) {
        const float hprev = rstE[i] ? 0.f : hp[i];
        const float rg = fast_sigmoid(giR[i] + sR[i]);
        const float zg = fast_sigmoid(giZ[i] + sZ[i]);
        const float ng = fast_tanh(giN[i] + rg * (sN[i] + bnj));
        hnew[i] = (1.0f - zg) * ng + zg * hprev;
        hp[i] = hnew[i];
        hshW[wave][brow0 - bg0 + i][lane & 7] = __float2bfloat16(hnew[i]);
      }
      // publish h_t to slot t+1 (plain + MALL mirror)
      ull pv = *reinterpret_cast<const ull*>(&hshW[wave][lane >> 1][(lane & 1) * 4]);
      st8_pub(hseqB + (size_t)(t + 1) * 131072 +
                  ((size_t)(bg0 + (lane >> 1)) * HH + j0 + 8 * wave + (lane & 1) * 4) * 2,
              pv);
      // ys (off the critical path)
      float* ys = out + 65536 + (size_t)t * 65536;
#pragma unroll
      for (int i = 0; i < 4; ++i)
        __builtin_nontemporal_store(hnew[i], &ys[(size_t)(brow0 + i) * HH + colg]);
      // prefetch next step's gi / resets
      const int tn = (t + 1 < TT) ? t + 1 : t;
#pragma unroll
      for (int i = 0; i < 4; ++i) {
        const int b = brow0 + i;
        rstE[i] = resets[tn * BB + b];
        if (GIF32) {
          const float* grow = reinterpret_cast<const float*>(gi_) + (size_t)(tn * BB + b) * H3;
          giR[i] = grow[colg]; giZ[i] = grow[HH + colg]; giN[i] = grow[2 * HH + colg];
        } else {
          const __hip_bfloat16* grow =
              reinterpret_cast<const __hip_bfloat16*>(gi_) + (size_t)(tn * BB + b) * H3;
          giR[i] = __bfloat162float(grow[colg]);
          giZ[i] = __bfloat162float(grow[HH + colg]);
          giN[i] = __bfloat162float(grow[2 * HH + colg]);
        }
      }
    }
  }

  if (lane < 16) {
#pragma unroll
    for (int i = 0; i < 4; ++i)
      out[(size_t)(brow0 + i) * HH + colg] = hp[i];
  }
}

// ---------------- launch ----------------

extern "C" void kernel_launch(void* const* d_in, const int* in_sizes, int n_in,
                              void* d_out, int out_size, void* d_ws, size_t ws_size,
                              hipStream_t stream) {
  const float* x      = (const float*)d_in[0];  // [256,64,1024]
  const int* resets   = (const int*)d_in[1];    // [256,64]
  const float* h0     = (const float*)d_in[2];  // [64,1024]
  const float* Wi     = (const float*)d_in[3];  // [1024,3072]
  const float* bi     = (const float*)d_in[4];  // [3072]
  const float* Wh     = (const float*)d_in[5];  // [1024,3072]
  const float* bn     = (const float*)d_in[6];  // [1024]
  (void)in_sizes; (void)n_in; (void)out_size;

  char* ws = (char*)d_ws;
  // region0: xb [16384][1024] bf16 (33,554,432 B), dead after gemm, then
  //          reused as hseq [257][64][1024] bf16 (33,685,504 B)
  __hip_bfloat16* xb   = (__hip_bfloat16*)(ws);
  __hip_bfloat16* hseq = (__hip_bfloat16*)(ws);
  __hip_bfloat16* WiT  = (__hip_bfloat16*)(ws + 33685504);  // 6,291,456 B
  __hip_bfloat16* WhT  = (__hip_bfloat16*)(ws + 39976960);  // 6,291,456 B
  void* gi             = (void*)(ws + 46268416);

  const bool gif32 = ws_size >= 46268416ull + (size_t)16384 * 3072 * 4;

  k_cvt_x<<<16384, 256, 0, stream>>>(x, xb, TT * BB * HH);
  k_transpose_w<<<dim3(96, 32), 256, 0, stream>>>(Wi, WiT);
  k_transpose_w<<<dim3(96, 32), 256, 0, stream>>>(Wh, WhT);
  if (gif32) {
    k_gemm_gi<true><<<3072, 256, 0, stream>>>(xb, WiT, bi, gi);
    // xb dead; sentinel-fill hseq with agent-scope stores
    k_fill_sentinel<<<2048, 256, 0, stream>>>((ull*)hseq, 33685504 / 8);
    k_gru<true><<<256, 256, 0, stream>>>(gi, resets, h0, bn, WhT, hseq, (float*)d_out);
  } else {
    k_gemm_gi<false><<<3072, 256, 0, stream>>>(xb, WiT, bi, gi);
    k_fill_sentinel<<<2048, 256, 0, stream>>>((ull*)hseq, 33685504 / 8);
    k_gru<false><<<256, 256, 0, stream>>>(gi, resets, h0, bn, WhT, hseq, (float*)d_out);
  }
}

// Round 8
// 2196.230 us; speedup vs baseline: 1.2442x; 1.2442x over previous
//
#include <hip/hip_runtime.h>
#include <hip/hip_bf16.h>
#include <cstdint>

// GRU scan: T=256, B=64, H=1024.
// gi = x@Wi + bi via bf16 MFMA GEMM; then a persistent 256-WG x 256-thread
// kernel walks the 256 sequential steps.
// Roles are blockIdx-derived ONLY (no runtime claims): group g = wg&7 owns
// batches [8g,8g+8); WG s = wg>>3 owns j-cols [32s,32s+32). If the hardware
// round-robins WGs over XCDs (standard), group g is XCD-local and the fast
// path below wins; if not, the sc1 fallback keeps it correct (round-5 path).
// h exchange: sentinel-in-data slots hseq[257][64][1024] bf16. A word is
// ready iff != 0xFFFF... (sentinel) and != 0xAAAA... (harness poison).
// Publish = plain store (producer-local L2) + sc0 sc1 mirror (MALL).
// Poll = bounded sc0 probes (local L2), hysteresis-escalate to sc1 (MALL).
// Full sentinel refill kernel each launch -> replay-safe.

#define TT 256
#define BB 64
#define HH 1024
#define H3 3072

typedef __attribute__((ext_vector_type(8))) short s16x8;
typedef __attribute__((ext_vector_type(4))) float f32x4;
typedef __attribute__((ext_vector_type(4))) unsigned int u32x4;
typedef unsigned long long ull;

__device__ __forceinline__ float fast_sigmoid(float x) {
  float e = __expf(-fabsf(x));
  float s = 1.0f / (1.0f + e);
  return x >= 0.0f ? s : 1.0f - s;
}
__device__ __forceinline__ float fast_tanh(float x) {
  float e = __expf(-2.0f * fabsf(x));
  float t = (1.0f - e) / (1.0f + e);
  return x >= 0.0f ? t : -t;
}
__device__ __forceinline__ f32x4 mfma16(s16x8 a, s16x8 b, f32x4 c) {
  return __builtin_amdgcn_mfma_f32_16x16x32_bf16(a, b, c, 0, 0, 0);
}

// 16B fragment not-ready test: any 8B half == sentinel (0xFF..) or poison (0xAA..)
__device__ __forceinline__ unsigned bad16(const u32x4& v) {
  unsigned s = (unsigned)(((v[0] & v[1]) == ~0u) | ((v[2] & v[3]) == ~0u));
  unsigned p = (unsigned)(((v[0] == 0xAAAAAAAAu) & (v[1] == 0xAAAAAAAAu)) |
                          ((v[2] == 0xAAAAAAAAu) & (v[3] == 0xAAAAAAAAu)));
  return s | p;
}

// 2-probe canary load, sc0 (local L2) / sc1 (MALL) variants
__device__ __forceinline__ void can0(u32x4& c0, u32x4& c1, const char* b) {
  asm volatile("global_load_dwordx4 %0, %2, off sc0\n\t"
               "global_load_dwordx4 %1, %2, off offset:512 sc0\n\t"
               "s_waitcnt vmcnt(0)"
               : "=&v"(c0), "=&v"(c1) : "v"(b) : "memory");
}
__device__ __forceinline__ void can1(u32x4& c0, u32x4& c1, const char* b) {
  asm volatile("global_load_dwordx4 %0, %2, off sc0 sc1\n\t"
               "global_load_dwordx4 %1, %2, off offset:512 sc0 sc1\n\t"
               "s_waitcnt vmcnt(0)"
               : "=&v"(c0), "=&v"(c1) : "v"(b) : "memory");
}

// 8 x 16B chunk load (64B stride), single waitcnt; sc0 / sc1 variants
__device__ __forceinline__ void ld8_sc0(u32x4* W, const char* b) {
  asm volatile(
      "global_load_dwordx4 %0, %8, off sc0\n\t"
      "global_load_dwordx4 %1, %8, off offset:64 sc0\n\t"
      "global_load_dwordx4 %2, %8, off offset:128 sc0\n\t"
      "global_load_dwordx4 %3, %8, off offset:192 sc0\n\t"
      "global_load_dwordx4 %4, %8, off offset:256 sc0\n\t"
      "global_load_dwordx4 %5, %8, off offset:320 sc0\n\t"
      "global_load_dwordx4 %6, %8, off offset:384 sc0\n\t"
      "global_load_dwordx4 %7, %8, off offset:448 sc0\n\t"
      "s_waitcnt vmcnt(0)"
      : "=&v"(W[0]), "=&v"(W[1]), "=&v"(W[2]), "=&v"(W[3]),
        "=&v"(W[4]), "=&v"(W[5]), "=&v"(W[6]), "=&v"(W[7])
      : "v"(b) : "memory");
}
__device__ __forceinline__ void ld8_sc1(u32x4* W, const char* b) {
  asm volatile(
      "global_load_dwordx4 %0, %8, off sc0 sc1\n\t"
      "global_load_dwordx4 %1, %8, off offset:64 sc0 sc1\n\t"
      "global_load_dwordx4 %2, %8, off offset:128 sc0 sc1\n\t"
      "global_load_dwordx4 %3, %8, off offset:192 sc0 sc1\n\t"
      "global_load_dwordx4 %4, %8, off offset:256 sc0 sc1\n\t"
      "global_load_dwordx4 %5, %8, off offset:320 sc0 sc1\n\t"
      "global_load_dwordx4 %6, %8, off offset:384 sc0 sc1\n\t"
      "global_load_dwordx4 %7, %8, off offset:448 sc0 sc1\n\t"
      "s_waitcnt vmcnt(0)"
      : "=&v"(W[0]), "=&v"(W[1]), "=&v"(W[2]), "=&v"(W[3]),
        "=&v"(W[4]), "=&v"(W[5]), "=&v"(W[6]), "=&v"(W[7])
      : "v"(b) : "memory");
}

// plain 16B load through asm: opaque to the compiler -> cannot rematerialize
__device__ __forceinline__ u32x4 ld16_opaque(const char* p) {
  u32x4 r;
  asm volatile("global_load_dwordx4 %0, %1, off\n\t"
               "s_waitcnt vmcnt(0)"
               : "=&v"(r) : "v"(p) : "memory");
  return r;
}

// publish 2B: plain (producer-local L2) + sc0 sc1 mirror (MALL)
__device__ __forceinline__ void st2_pub(char* p, unsigned v) {
  asm volatile("global_store_short %0, %1, off\n\t"
               "global_store_short %0, %1, off sc0 sc1"
               :: "v"(p), "v"(v) : "memory");
}

// ---------------- setup kernels ----------------

__global__ void k_cvt_x(const float* __restrict__ x, __hip_bfloat16* __restrict__ xb, int n) {
  int i = (blockIdx.x * blockDim.x + threadIdx.x) * 4;
  if (i + 3 < n) {
    float4 v = *reinterpret_cast<const float4*>(x + i);
    xb[i + 0] = __float2bfloat16(v.x);
    xb[i + 1] = __float2bfloat16(v.y);
    xb[i + 2] = __float2bfloat16(v.z);
    xb[i + 3] = __float2bfloat16(v.w);
  }
}

// W [1024][3072] f32 -> WT [3072][1024] bf16
__global__ void k_transpose_w(const float* __restrict__ W, __hip_bfloat16* __restrict__ WT) {
  __shared__ float tile[32][33];
  int c0 = blockIdx.x * 32, r0 = blockIdx.y * 32;
  int tx = threadIdx.x & 31, ty = threadIdx.x >> 5;
#pragma unroll
  for (int i = 0; i < 32; i += 8)
    tile[ty + i][tx] = W[(size_t)(r0 + ty + i) * H3 + c0 + tx];
  __syncthreads();
#pragma unroll
  for (int i = 0; i < 32; i += 8)
    WT[(size_t)(c0 + ty + i) * HH + r0 + tx] = __float2bfloat16(tile[tx][ty + i]);
}

// full sentinel refill, agent-scope (MALL) — replay-safety anchor
__global__ void k_fill_sentinel(ull* __restrict__ p, int nwords) {
  int idx = blockIdx.x * blockDim.x + threadIdx.x;
  for (int i = idx; i < nwords; i += gridDim.x * blockDim.x)
    __hip_atomic_store(p + i, ~0ull, __ATOMIC_RELAXED, __HIP_MEMORY_SCOPE_AGENT);
}

// ---------------- gi = x @ Wi + bi  (bf16 MFMA, 128x128 tile, BK=32) ----------------

template <bool GIF32>
__global__ __launch_bounds__(256, 2) void k_gemm_gi(
    const __hip_bfloat16* __restrict__ A,
    const __hip_bfloat16* __restrict__ Bt,
    const float* __restrict__ bi,
    void* __restrict__ gi) {
  __shared__ __align__(16) __hip_bfloat16 As[128 * 32];
  __shared__ __align__(16) __hip_bfloat16 Bs[128 * 32];
  const int bid = blockIdx.x;
  const int mt = bid / 24, nt = bid % 24;
  const int m0 = mt * 128, n0 = nt * 128;
  const int tid = threadIdx.x, lane = tid & 63, w = tid >> 6;
  const int wm = w & 1, wn = w >> 1;

  f32x4 acc[4][4];
#pragma unroll
  for (int ai = 0; ai < 4; ++ai)
#pragma unroll
    for (int bj = 0; bj < 4; ++bj) acc[ai][bj] = (f32x4){0.f, 0.f, 0.f, 0.f};

  for (int k0 = 0; k0 < HH; k0 += 32) {
#pragma unroll
    for (int i = 0; i < 2; ++i) {
      const int c = w + i * 4;
      const int idx = c * 64 + lane;
      const int row = idx >> 2, slot = idx & 3;
      __builtin_amdgcn_global_load_lds(
          (const __attribute__((address_space(1))) void*)(A + (size_t)(m0 + row) * HH + k0 + slot * 8),
          (__attribute__((address_space(3))) void*)(As + c * 512), 16, 0, 0);
      __builtin_amdgcn_global_load_lds(
          (const __attribute__((address_space(1))) void*)(Bt + (size_t)(n0 + row) * HH + k0 + slot * 8),
          (__attribute__((address_space(3))) void*)(Bs + c * 512), 16, 0, 0);
    }
    __syncthreads();
    s16x8 af[4], bf[4];
#pragma unroll
    for (int ai = 0; ai < 4; ++ai) {
      int r = wm * 64 + ai * 16 + (lane & 15);
      af[ai] = *reinterpret_cast<const s16x8*>(As + r * 32 + (lane >> 4) * 8);
    }
#pragma unroll
    for (int bj = 0; bj < 4; ++bj) {
      int r = wn * 64 + bj * 16 + (lane & 15);
      bf[bj] = *reinterpret_cast<const s16x8*>(Bs + r * 32 + (lane >> 4) * 8);
    }
#pragma unroll
    for (int ai = 0; ai < 4; ++ai)
#pragma unroll
      for (int bj = 0; bj < 4; ++bj) acc[ai][bj] = mfma16(af[ai], bf[bj], acc[ai][bj]);
    __syncthreads();
  }

#pragma unroll
  for (int ai = 0; ai < 4; ++ai) {
#pragma unroll
    for (int reg = 0; reg < 4; ++reg) {
      const size_t row = (size_t)m0 + wm * 64 + ai * 16 + (lane >> 4) * 4 + reg;
#pragma unroll
      for (int bj = 0; bj < 4; ++bj) {
        const int col = n0 + wn * 64 + bj * 16 + (lane & 15);
        float v = acc[ai][bj][reg] + bi[col];
        if (GIF32)
          reinterpret_cast<float*>(gi)[row * H3 + col] = v;
        else
          reinterpret_cast<__hip_bfloat16*>(gi)[row * H3 + col] = __float2bfloat16(v);
      }
    }
  }
}

// ---------------- persistent step kernel ----------------

// 256 WGs x 256 threads. Group g = wg&7: batches [8g,8g+8).
// WG s = wg>>3: j-cols [32s,32s+32). Wave w: jt=w&1 (16-col half),
// kh=w>>1 (512-K half) -> 48 MFMA/wave/step. Epilogue: thread owns one (b,j).
template <bool GIF32>
__global__ __launch_bounds__(256, 1) void k_gru(
    const void* __restrict__ gi_,
    const int* __restrict__ resets,   // [256][64]
    const float* __restrict__ h0,     // [64][1024]
    const float* __restrict__ bn,     // [1024]
    const __hip_bfloat16* __restrict__ WhT,  // [3072][1024]
    __hip_bfloat16* hseq,                    // [257][64][1024] sentinel-filled
    float* __restrict__ out) {               // [64*1024 hfinal | 256*64*1024 ys]
  __shared__ __align__(16) char Wlds[64 * 2048];   // gates r,z (128 KiB), XOR-swizzled
  __shared__ __align__(16) f32x4 part[2][4][64];   // per-parity, tile, lane... (see below)
  __shared__ __align__(16) f32x4 part2[2][8][64];  // split to keep indices simple

  const int tid = threadIdx.x;
  const int wave = tid >> 6, lane = tid & 63;
  const int wg = blockIdx.x;
  const int g = wg & 7, s = wg >> 3;
  const int bg0 = g * 8, j0 = s * 32;
  const int jt = wave & 1, kh = wave >> 1;

  // stage Wh gates r,z into LDS (rows: 0-31 = gate r cols j0.., 32-63 = gate z)
  for (int u = tid; u < 64 * 128; u += 256) {
    const int row = u >> 7, sl = u & 127;
    const int gate = row >> 5, jj = row & 31;
    u32x4 v = *reinterpret_cast<const u32x4*>(WhT + (size_t)(gate * HH + j0 + jj) * HH + sl * 8);
    const int byte = row * 2048 + ((sl * 16) ^ ((row & 7) << 4));
    *reinterpret_cast<u32x4*>(Wlds + byte) = v;
  }

  // gate n fragments in registers via opaque asm loads (non-rematerializable)
  u32x4 bnfr[16];
  {
    const char* bp = reinterpret_cast<const char*>(
        WhT + (size_t)(2 * HH + j0 + jt * 16 + (lane & 15)) * HH + kh * 512 + (lane >> 4) * 8);
#pragma unroll
    for (int kk = 0; kk < 16; ++kk) bnfr[kk] = ld16_opaque(bp + kk * 64);
  }

  // per-thread epilogue identity
  const int eb = tid >> 5, ej = tid & 31;
  const int brow = bg0 + eb, col = j0 + ej;
  const float bnj = bn[col];
  float hp = h0[(size_t)brow * HH + col];

  char* const hq = reinterpret_cast<char*>(hseq);
  const size_t myoff = (size_t)brow * 2048 + (size_t)col * 2;

  // publish h_{-1} into slot 0 (plain + mirror). Sentinel protocol is the barrier.
  st2_pub(hq + myoff, (unsigned)__builtin_bit_cast(unsigned short, __float2bfloat16(hp)));

  // step-0 gi / reset prefetch
  float giR, giZ, giN;
  int rstE = resets[brow];
  if (GIF32) {
    const float* grow = reinterpret_cast<const float*>(gi_) + (size_t)brow * H3;
    giR = grow[col]; giZ = grow[HH + col]; giN = grow[2 * HH + col];
  } else {
    const __hip_bfloat16* grow = reinterpret_cast<const __hip_bfloat16*>(gi_) + (size_t)brow * H3;
    giR = __bfloat162float(grow[col]);
    giZ = __bfloat162float(grow[HH + col]);
    giN = __bfloat162float(grow[2 * HH + col]);
  }

  // poll geometry: row = bg0 + (lane&7), this wave's K half
  const size_t abase = (size_t)(bg0 + (lane & 7)) * 2048 + (size_t)kh * 1024 + (size_t)(lane >> 4) * 16;
  const size_t cbase = (size_t)(bg0 + (lane & 7)) * 2048 + (size_t)kh * 1024 + (size_t)(lane >> 3) * 64;
  const int rbR = jt * 16 + (lane & 15);
  const int rbZ = 32 + jt * 16 + (lane & 15);
  __syncthreads();  // Wlds staged

  int fastEn = 1, escn = 0;

  for (int t = 0; t < TT; ++t) {
    const int p = t & 1;
    const int rstA = resets[t * BB + bg0 + (lane & 7)];
    const char* cb = hq + (size_t)t * 131072 + abase;
    const char* cc = hq + (size_t)t * 131072 + cbase;

    // ---- canary: fast sc0 probes, fallback sc1 (guaranteed path) ----
    bool fastOK = false;
    if (fastEn) {
      for (int it = 0; it < 24; ++it) {
        u32x4 c0, c1;
        can0(c0, c1, cc);
        if (!__any((int)(bad16(c0) | bad16(c1)))) { fastOK = true; break; }
      }
      if (fastOK) escn = 0;
      else if (++escn >= 3) fastEn = 0;  // hysteresis: stop wasting fast probes
    }
    if (!fastOK) {
      int gq = 0;
      u32x4 c0, c1;
      do {
        can1(c0, c1, cc);
        if (!__any((int)(bad16(c0) | bad16(c1)))) break;
      } while (++gq < (1 << 22));
    }

    // ---- full chunk (16 x 16B, 64B stride) + verify ----
    u32x4 W[16];
    if (fastOK) { ld8_sc0(W, cb); ld8_sc0(W + 8, cb + 512); }
    else        { ld8_sc1(W, cb); ld8_sc1(W + 8, cb + 512); }
    {
      int r = 0;
      for (;;) {
        unsigned bad = 0;
#pragma unroll
        for (int i = 0; i < 16; ++i) bad |= bad16(W[i]);
        if (!__any((int)bad)) break;
        if (++r > (1 << 20)) break;
        if (fastOK && r <= 4) { ld8_sc0(W, cb); ld8_sc0(W + 8, cb + 512); }
        else                  { ld8_sc1(W, cb); ld8_sc1(W + 8, cb + 512); }
      }
    }

    // ---- 48 MFMA: r,z from LDS; n from registers ----
    const unsigned vm = (((lane & 15) < 8) && !rstA) ? ~0u : 0u;
    f32x4 aR = {0.f, 0.f, 0.f, 0.f}, aZ = {0.f, 0.f, 0.f, 0.f}, aN = {0.f, 0.f, 0.f, 0.f};
#pragma unroll
    for (int kk = 0; kk < 16; ++kk) {
      u32x4 m = W[kk];
      m[0] &= vm; m[1] &= vm; m[2] &= vm; m[3] &= vm;
      s16x8 a = __builtin_bit_cast(s16x8, m);
      const int kb = (kh * 16 + kk) * 64 + (lane >> 4) * 16;
      s16x8 br = *reinterpret_cast<const s16x8*>(Wlds + rbR * 2048 + (kb ^ ((rbR & 7) << 4)));
      s16x8 bz = *reinterpret_cast<const s16x8*>(Wlds + rbZ * 2048 + (kb ^ ((rbZ & 7) << 4)));
      aR = mfma16(a, br, aR);
      aZ = mfma16(a, bz, aZ);
      aN = mfma16(a, __builtin_bit_cast(s16x8, bnfr[kk]), aN);
    }
    // tiles: jt*2+kh in [0,4)
    part[p][jt * 2 + kh][lane] = aR;
    part2[p][0 + jt * 2 + kh][lane] = aZ;
    part2[p][4 + jt * 2 + kh][lane] = aN;
    __syncthreads();

    // ---- epilogue: each thread one (b,j) cell ----
    const int li = (eb >> 2) * 16 + (ej & 15), el = eb & 3;
    const int ejt = (ej >> 4) * 2;
    const float sR = part[p][ejt + 0][li][el] + part[p][ejt + 1][li][el];
    const float sZ = part2[p][0 + ejt + 0][li][el] + part2[p][0 + ejt + 1][li][el];
    const float sN = part2[p][4 + ejt + 0][li][el] + part2[p][4 + ejt + 1][li][el];
    const float hprev = rstE ? 0.f : hp;
    const float rg = fast_sigmoid(giR + sR);
    const float zg = fast_sigmoid(giZ + sZ);
    const float ng = fast_tanh(giN + rg * (sN + bnj));
    const float hnew = (1.0f - zg) * ng + zg * hprev;
    hp = hnew;
    // publish h_t into slot t+1 (plain + mirror), FIRST
    st2_pub(hq + (size_t)(t + 1) * 131072 + myoff,
            (unsigned)__builtin_bit_cast(unsigned short, __float2bfloat16(hnew)));
    // ys write (off the inter-WG critical path)
    __builtin_nontemporal_store(hnew, out + 65536 + (size_t)t * 65536 + (size_t)brow * HH + col);
    // prefetch next step's gi / reset
    const int tn = (t + 1 < TT) ? t + 1 : t;
    rstE = resets[tn * BB + brow];
    if (GIF32) {
      const float* grow = reinterpret_cast<const float*>(gi_) + (size_t)(tn * BB + brow) * H3;
      giR = grow[col]; giZ = grow[HH + col]; giN = grow[2 * HH + col];
    } else {
      const __hip_bfloat16* grow =
          reinterpret_cast<const __hip_bfloat16*>(gi_) + (size_t)(tn * BB + brow) * H3;
      giR = __bfloat162float(grow[col]);
      giZ = __bfloat162float(grow[HH + col]);
      giN = __bfloat162float(grow[2 * HH + col]);
    }
  }

  out[(size_t)brow * HH + col] = hp;
}

// ---------------- launch ----------------

extern "C" void kernel_launch(void* const* d_in, const int* in_sizes, int n_in,
                              void* d_out, int out_size, void* d_ws, size_t ws_size,
                              hipStream_t stream) {
  const float* x      = (const float*)d_in[0];  // [256,64,1024]
  const int* resets   = (const int*)d_in[1];    // [256,64]
  const float* h0     = (const float*)d_in[2];  // [64,1024]
  const float* Wi     = (const float*)d_in[3];  // [1024,3072]
  const float* bi     = (const float*)d_in[4];  // [3072]
  const float* Wh     = (const float*)d_in[5];  // [1024,3072]
  const float* bn     = (const float*)d_in[6];  // [1024]
  (void)in_sizes; (void)n_in; (void)out_size;

  char* ws = (char*)d_ws;
  __hip_bfloat16* xb   = (__hip_bfloat16*)(ws);             // 33,554,432 B
  __hip_bfloat16* WiT  = (__hip_bfloat16*)(ws + 33554432);  //  6,291,456 B
  __hip_bfloat16* WhT  = (__hip_bfloat16*)(ws + 39845888);  //  6,291,456 B
  // hseq DEDICATED (never aliased): group-g rows only ever written by group g.
  __hip_bfloat16* hseq = (__hip_bfloat16*)(ws + 46137344);  // 33,685,504 B
  void* gi             = (void*)(ws + 79822848);

  const bool gif32 = ws_size >= 79822848ull + (size_t)16384 * 3072 * 4;

  k_cvt_x<<<16384, 256, 0, stream>>>(x, xb, TT * BB * HH);
  k_transpose_w<<<dim3(96, 32), 256, 0, stream>>>(Wi, WiT);
  k_transpose_w<<<dim3(96, 32), 256, 0, stream>>>(Wh, WhT);
  k_fill_sentinel<<<2048, 256, 0, stream>>>((ull*)hseq, 33685504 / 8);
  if (gif32) {
    k_gemm_gi<true><<<3072, 256, 0, stream>>>(xb, WiT, bi, gi);
    k_gru<true><<<256, 256, 0, stream>>>(gi, resets, h0, bn, WhT, hseq, (float*)d_out);
  } else {
    k_gemm_gi<false><<<3072, 256, 0, stream>>>(xb, WiT, bi, gi);
    k_gru<false><<<256, 256, 0, stream>>>(gi, resets, h0, bn, WhT, hseq, (float*)d_out);
  }
}

// Round 9
// 1546.869 us; speedup vs baseline: 1.7664x; 1.4198x over previous
//
#include <hip/hip_runtime.h>
#include <hip/hip_bf16.h>
#include <cstdint>

// GRU scan: T=256, B=64, H=1024.
// gi = x@Wi + bi precomputed with one bf16 MFMA GEMM; then a persistent
// 256-WG x 256-thread kernel walks 256 sequential steps.
// Round-5 skeleton (best measured) + producer DONE-FLAG protocol:
//   producer: publish 8B agent stores -> s_waitcnt vmcnt(0) -> 8B flag stamp.
//   consumer wave w: poll the 16 flags of its K-chunk's producers (1 per
//   lane, 4x redundant) until >= t+1, then ONE bulk load (no verify).
// Flags are monotonic step-stamps, zeroed per launch (2 KB) -> replay-safe;
// no sentinel fill, no data validation, no poison hazard.

#define TT 256
#define BB 64
#define HH 1024
#define H3 3072

typedef __attribute__((ext_vector_type(8))) short s16x8;
typedef __attribute__((ext_vector_type(4))) float f32x4;
typedef __attribute__((ext_vector_type(4))) unsigned int u32x4;
typedef unsigned long long ull;

__device__ __forceinline__ float fast_sigmoid(float x) {
  float e = __expf(-fabsf(x));
  float s = 1.0f / (1.0f + e);
  return x >= 0.0f ? s : 1.0f - s;
}
__device__ __forceinline__ float fast_tanh(float x) {
  float e = __expf(-2.0f * fabsf(x));
  float t = (1.0f - e) / (1.0f + e);
  return x >= 0.0f ? t : -t;
}
__device__ __forceinline__ f32x4 mfma16(s16x8 a, s16x8 b, f32x4 c) {
  return __builtin_amdgcn_mfma_f32_16x16x32_bf16(a, b, c, 0, 0, 0);
}

#define LD8(p) __hip_atomic_load((p), __ATOMIC_RELAXED, __HIP_MEMORY_SCOPE_AGENT)

// ---------------- setup kernels ----------------

__global__ void k_cvt_x(const float* __restrict__ x, __hip_bfloat16* __restrict__ xb, int n) {
  int i = (blockIdx.x * blockDim.x + threadIdx.x) * 4;
  if (i + 3 < n) {
    float4 v = *reinterpret_cast<const float4*>(x + i);
    xb[i + 0] = __float2bfloat16(v.x);
    xb[i + 1] = __float2bfloat16(v.y);
    xb[i + 2] = __float2bfloat16(v.z);
    xb[i + 3] = __float2bfloat16(v.w);
  }
}

// W [1024][3072] f32 -> WT [3072][1024] bf16
__global__ void k_transpose_w(const float* __restrict__ W, __hip_bfloat16* __restrict__ WT) {
  __shared__ float tile[32][33];
  int c0 = blockIdx.x * 32, r0 = blockIdx.y * 32;
  int tx = threadIdx.x & 31, ty = threadIdx.x >> 5;  // 256 threads: 32x8
#pragma unroll
  for (int i = 0; i < 32; i += 8)
    tile[ty + i][tx] = W[(size_t)(r0 + ty + i) * H3 + c0 + tx];
  __syncthreads();
#pragma unroll
  for (int i = 0; i < 32; i += 8)
    WT[(size_t)(c0 + ty + i) * HH + r0 + tx] = __float2bfloat16(tile[tx][ty + i]);
}

// ---------------- gi = x @ Wi + bi  (bf16 MFMA, 128x128 tile, BK=32) ----------------

template <bool GIF32>
__global__ __launch_bounds__(256, 2) void k_gemm_gi(
    const __hip_bfloat16* __restrict__ A,   // [16384][1024] x bf16
    const __hip_bfloat16* __restrict__ Bt,  // [3072][1024]  Wi^T bf16
    const float* __restrict__ bi,           // [3072]
    void* __restrict__ gi)                  // [16384][3072] f32 or bf16
{
  __shared__ __align__(16) __hip_bfloat16 As[128 * 32];
  __shared__ __align__(16) __hip_bfloat16 Bs[128 * 32];
  const int bid = blockIdx.x;
  const int mt = bid / 24, nt = bid % 24;
  const int m0 = mt * 128, n0 = nt * 128;
  const int tid = threadIdx.x, lane = tid & 63, w = tid >> 6;
  const int wm = w & 1, wn = w >> 1;

  f32x4 acc[4][4];
#pragma unroll
  for (int ai = 0; ai < 4; ++ai)
#pragma unroll
    for (int bj = 0; bj < 4; ++bj) acc[ai][bj] = (f32x4){0.f, 0.f, 0.f, 0.f};

  for (int k0 = 0; k0 < HH; k0 += 32) {
#pragma unroll
    for (int i = 0; i < 2; ++i) {
      const int c = w + i * 4;          // 1KB chunk id, wave-uniform
      const int idx = c * 64 + lane;    // 16B unit id
      const int row = idx >> 2, slot = idx & 3;
      __builtin_amdgcn_global_load_lds(
          (const __attribute__((address_space(1))) void*)(A + (size_t)(m0 + row) * HH + k0 + slot * 8),
          (__attribute__((address_space(3))) void*)(As + c * 512), 16, 0, 0);
      __builtin_amdgcn_global_load_lds(
          (const __attribute__((address_space(1))) void*)(Bt + (size_t)(n0 + row) * HH + k0 + slot * 8),
          (__attribute__((address_space(3))) void*)(Bs + c * 512), 16, 0, 0);
    }
    __syncthreads();
    s16x8 af[4], bf[4];
#pragma unroll
    for (int ai = 0; ai < 4; ++ai) {
      int r = wm * 64 + ai * 16 + (lane & 15);
      af[ai] = *reinterpret_cast<const s16x8*>(As + r * 32 + (lane >> 4) * 8);
    }
#pragma unroll
    for (int bj = 0; bj < 4; ++bj) {
      int r = wn * 64 + bj * 16 + (lane & 15);
      bf[bj] = *reinterpret_cast<const s16x8*>(Bs + r * 32 + (lane >> 4) * 8);
    }
#pragma unroll
    for (int ai = 0; ai < 4; ++ai)
#pragma unroll
      for (int bj = 0; bj < 4; ++bj) acc[ai][bj] = mfma16(af[ai], bf[bj], acc[ai][bj]);
    __syncthreads();
  }

#pragma unroll
  for (int ai = 0; ai < 4; ++ai) {
#pragma unroll
    for (int reg = 0; reg < 4; ++reg) {
      const size_t row = (size_t)m0 + wm * 64 + ai * 16 + (lane >> 4) * 4 + reg;
#pragma unroll
      for (int bj = 0; bj < 4; ++bj) {
        const int col = n0 + wn * 64 + bj * 16 + (lane & 15);
        float v = acc[ai][bj][reg] + bi[col];
        if (GIF32)
          reinterpret_cast<float*>(gi)[row * H3 + col] = v;
        else
          reinterpret_cast<__hip_bfloat16*>(gi)[row * H3 + col] = __float2bfloat16(v);
      }
    }
  }
}

// ---------------- persistent step kernel ----------------

// 256 WGs x 256 threads (4 waves). 4 groups (16 batches) x 64 WGs (16 j-cols).
// Wh^T slice (48 rows x 1024 k, 96 KiB) LDS-resident with XOR swizzle.
// Wave w polls its 16 producers' flags then bulk-loads K-chunk w;
// wave 0 reduces + epilogues + publishes + stamps this WG's flag.
template <bool GIF32>
__global__ __launch_bounds__(256, 1) void k_gru(
    const void* __restrict__ gi_,
    const int* __restrict__ resets,   // [256][64]
    const float* __restrict__ h0,     // [64][1024]
    const float* __restrict__ bn,     // [1024]
    const __hip_bfloat16* __restrict__ WhT,  // [3072][1024]
    __hip_bfloat16* hseq,                    // [257][64][1024]
    ull* flags,                              // [4][64] step stamps, zeroed
    float* __restrict__ out)                 // [64*1024 hfinal | 256*64*1024 ys]
{
  __shared__ __align__(16) __hip_bfloat16 Bsh[48 * 1024];  // 96 KiB
  __shared__ __align__(16) f32x4 part[2][4][3][64];        // 24 KiB partials
  __shared__ __align__(8) __hip_bfloat16 hsh[16][16];      // 512 B transpose
  const int tid = threadIdx.x;
  const int wave = tid >> 6, lane = tid & 63;
  const int wg = blockIdx.x;
  const int g = (wg & 7) >> 1;                // XCD-pair -> group (perf heuristic only)
  const int s = ((wg >> 3) << 1) | (wg & 1);  // 0..63 within group
  const int bg0 = g * 16, j0 = s * 16;
  ull* const myflag = flags + g * 64 + s;

  // stage Wh^T slice into LDS, XOR-swizzled: data(row, slot16B) at byte
  // row*2048 + ((slot*16) ^ ((row&7)<<4))
  for (int cch = tid; cch < 48 * 128; cch += 256) {
    const int row = cch >> 7, slot = cch & 127;
    const int gate = row >> 4, jj = row & 15;
    u32x4 v = *reinterpret_cast<const u32x4*>(WhT + (size_t)(gate * HH + j0 + jj) * HH + slot * 8);
    const int byte = row * 2048 + ((slot * 16) ^ ((row & 7) << 4));
    *reinterpret_cast<u32x4*>(reinterpret_cast<char*>(Bsh) + byte) = v;
  }

  const int jl = lane & 15;         // local j (C col)
  const int bh = (lane >> 4) * 4;   // C row base (batch-local)
  const int prow = lane >> 2, pq = (lane & 3) * 4;  // publish layout: 8B/lane
  const int al = lane & 15;         // A-fragment batch row (group-local)
  const int koff = (lane >> 4) * 8; // A-fragment k sub-offset (elements)
  const int j = j0 + jl;

  const char* bbase = reinterpret_cast<const char*>(Bsh);
  const int xsw = (jl & 7) << 4;
  const int rb0 = jl * 2048, rb1 = (16 + jl) * 2048, rb2 = (32 + jl) * 2048;

  float hp[4];
  float girC[4], gizC[4], ginC[4];
  int rstEC[4];
  float bnj = 0.f;

  if (wave == 0) {
    bnj = bn[j];
#pragma unroll
    for (int r = 0; r < 4; ++r) hp[r] = h0[(size_t)(bg0 + bh + r) * HH + j0 + jl];
    // publish slot 0 (= h_{-1}): LDS transpose -> coalesced 8B agent stores
#pragma unroll
    for (int r = 0; r < 4; ++r) hsh[bh + r][jl] = __float2bfloat16(hp[r]);
    ull pv = *reinterpret_cast<const ull*>(&hsh[prow][pq]);
    __hip_atomic_store(reinterpret_cast<ull*>(hseq + (size_t)g * 16384 + prow * HH + j0 + pq),
                       pv, __ATOMIC_RELAXED, __HIP_MEMORY_SCOPE_AGENT);
    asm volatile("s_waitcnt vmcnt(0)" ::: "memory");  // data ACKed at MALL
    if (lane == 0)
      __hip_atomic_store(myflag, 1ull, __ATOMIC_RELAXED, __HIP_MEMORY_SCOPE_AGENT);
    // prologue: step-0 gi / resets
#pragma unroll
    for (int r = 0; r < 4; ++r) {
      const int b = bg0 + bh + r;
      rstEC[r] = resets[b];
      if (GIF32) {
        const float* grow = reinterpret_cast<const float*>(gi_) + (size_t)b * H3;
        girC[r] = grow[j]; gizC[r] = grow[HH + j]; ginC[r] = grow[2 * HH + j];
      } else {
        const __hip_bfloat16* grow = reinterpret_cast<const __hip_bfloat16*>(gi_) + (size_t)b * H3;
        girC[r] = __bfloat162float(grow[j]);
        gizC[r] = __bfloat162float(grow[HH + j]);
        ginC[r] = __bfloat162float(grow[2 * HH + j]);
      }
    }
  }
  __syncthreads();  // Bsh staged

  // this wave's producers: K-chunk w covers j-cols of WGs [wave*16, wave*16+16)
  const ull* const pollflag = flags + g * 64 + wave * 16 + (lane & 15);

  for (int t = 0; t < TT; ++t) {
    const int rstA = resets[t * BB + bg0 + al];  // hidden under the wait
    const __hip_bfloat16* rd = hseq + (size_t)t * 65536 + g * 16384;
    const ull* ch = reinterpret_cast<const ull*>(rd + al * HH + koff) + wave * 64;

    // flag wait: all 16 producers of this chunk have published slot t
    {
      int gq = 0;
      ull f;
      do {
        f = LD8(pollflag);
      } while (__any((int)(f < (ull)(t + 1))) && ++gq < (1 << 14));
    }

    // ONE bulk load — flag ordering guarantees completeness, no verify
    ull w[16];
#pragma unroll
    for (int i = 0; i < 8; ++i) {
      w[2 * i + 0] = LD8(ch + i * 8 + 0);
      w[2 * i + 1] = LD8(ch + i * 8 + 1);
    }

    // 24 partial MFMAs for this wave's K-range
    const ull amask = rstA ? 0ull : ~0ull;
    f32x4 aR = {0.f, 0.f, 0.f, 0.f}, aZ = {0.f, 0.f, 0.f, 0.f}, aN = {0.f, 0.f, 0.f, 0.f};
#pragma unroll
    for (int i = 0; i < 8; ++i) {
      const int kk = wave * 8 + i;
      union { ull q[2]; s16x8 v; } u;
      u.q[0] = w[2 * i + 0] & amask;
      u.q[1] = w[2 * i + 1] & amask;
      const int kb = kk * 64 + (lane >> 4) * 16;
      s16x8 b0 = *reinterpret_cast<const s16x8*>(bbase + rb0 + (kb ^ xsw));
      s16x8 b1 = *reinterpret_cast<const s16x8*>(bbase + rb1 + (kb ^ xsw));
      s16x8 b2 = *reinterpret_cast<const s16x8*>(bbase + rb2 + (kb ^ xsw));
      aR = mfma16(u.v, b0, aR);
      aZ = mfma16(u.v, b1, aZ);
      aN = mfma16(u.v, b2, aN);
    }

    const int p = t & 1;
    part[p][wave][0][lane] = aR;
    part[p][wave][1][lane] = aZ;
    part[p][wave][2][lane] = aN;
    __syncthreads();  // partials visible (parity double-buffer -> one barrier)

    if (wave == 0) {
      f32x4 sR = part[p][0][0][lane], sZ = part[p][0][1][lane], sN = part[p][0][2][lane];
#pragma unroll
      for (int ww = 1; ww < 4; ++ww) {
        sR += part[p][ww][0][lane];
        sZ += part[p][ww][1][lane];
        sN += part[p][ww][2][lane];
      }
      float hnew[4];
#pragma unroll
      for (int r = 0; r < 4; ++r) {
        const float hprev = rstEC[r] ? 0.f : hp[r];
        const float rg = fast_sigmoid(girC[r] + sR[r]);
        const float zg = fast_sigmoid(gizC[r] + sZ[r]);
        const float ng = fast_tanh(ginC[r] + rg * (sN[r] + bnj));
        hnew[r] = (1.0f - zg) * ng + zg * hprev;
        hp[r] = hnew[r];
      }
      // publish h_t to slot t+1: LDS transpose -> coalesced 8B agent stores
#pragma unroll
      for (int r = 0; r < 4; ++r) hsh[bh + r][jl] = __float2bfloat16(hnew[r]);
      ull pv = *reinterpret_cast<const ull*>(&hsh[prow][pq]);
      __hip_atomic_store(
          reinterpret_cast<ull*>(hseq + (size_t)(t + 1) * 65536 + g * 16384 + prow * HH + j0 + pq),
          pv, __ATOMIC_RELAXED, __HIP_MEMORY_SCOPE_AGENT);
      asm volatile("s_waitcnt vmcnt(0)" ::: "memory");  // data ACKed at MALL
      if (lane == 0)
        __hip_atomic_store(myflag, (ull)(t + 2), __ATOMIC_RELAXED, __HIP_MEMORY_SCOPE_AGENT);

      // ys writes after the flag: off the inter-WG critical path
      float* ys = out + 65536 + (size_t)t * 65536;
#pragma unroll
      for (int r = 0; r < 4; ++r)
        __builtin_nontemporal_store(hnew[r], &ys[(size_t)(bg0 + bh + r) * HH + j]);

      // prefetch next step's gi / resets; consumed after next barrier
      const int tn = (t + 1 < TT) ? t + 1 : t;
#pragma unroll
      for (int r = 0; r < 4; ++r) {
        const int b = bg0 + bh + r;
        rstEC[r] = resets[tn * BB + b];
        if (GIF32) {
          const float* grow = reinterpret_cast<const float*>(gi_) + (size_t)(tn * BB + b) * H3;
          girC[r] = grow[j]; gizC[r] = grow[HH + j]; ginC[r] = grow[2 * HH + j];
        } else {
          const __hip_bfloat16* grow =
              reinterpret_cast<const __hip_bfloat16*>(gi_) + (size_t)(tn * BB + b) * H3;
          girC[r] = __bfloat162float(grow[j]);
          gizC[r] = __bfloat162float(grow[HH + j]);
          ginC[r] = __bfloat162float(grow[2 * HH + j]);
        }
      }
    }
  }

  if (wave == 0) {
#pragma unroll
    for (int r = 0; r < 4; ++r)
      out[(size_t)(bg0 + bh + r) * HH + j0 + jl] = hp[r];
  }
}

// ---------------- launch ----------------

extern "C" void kernel_launch(void* const* d_in, const int* in_sizes, int n_in,
                              void* d_out, int out_size, void* d_ws, size_t ws_size,
                              hipStream_t stream) {
  const float* x      = (const float*)d_in[0];  // [256,64,1024]
  const int* resets   = (const int*)d_in[1];    // [256,64]
  const float* h0     = (const float*)d_in[2];  // [64,1024]
  const float* Wi     = (const float*)d_in[3];  // [1024,3072]
  const float* bi     = (const float*)d_in[4];  // [3072]
  const float* Wh     = (const float*)d_in[5];  // [1024,3072]
  const float* bn     = (const float*)d_in[6];  // [1024]
  (void)in_sizes; (void)n_in; (void)out_size;

  char* ws = (char*)d_ws;
  // region0: xb [16384][1024] bf16 (33,554,432 B), dead after gemm, then
  //          reused as hseq [257][64][1024] bf16 (33,685,504 B).
  //          (Staleness is harmless: consumers only read slot t after its
  //           producer's flag, stamped THIS launch, confirms the data.)
  __hip_bfloat16* xb   = (__hip_bfloat16*)(ws);
  __hip_bfloat16* hseq = (__hip_bfloat16*)(ws);
  __hip_bfloat16* WiT  = (__hip_bfloat16*)(ws + 33685504);  // 6,291,456 B
  __hip_bfloat16* WhT  = (__hip_bfloat16*)(ws + 39976960);  // 6,291,456 B
  ull* flags           = (ull*)(ws + 46268416);             //     2,048 B
  void* gi             = (void*)(ws + 46270464);

  const bool gif32 = ws_size >= 46270464ull + (size_t)16384 * 3072 * 4;

  hipMemsetAsync(flags, 0, 2048, stream);
  k_cvt_x<<<16384, 256, 0, stream>>>(x, xb, TT * BB * HH);
  k_transpose_w<<<dim3(96, 32), 256, 0, stream>>>(Wi, WiT);
  k_transpose_w<<<dim3(96, 32), 256, 0, stream>>>(Wh, WhT);
  if (gif32) {
    k_gemm_gi<true><<<3072, 256, 0, stream>>>(xb, WiT, bi, gi);
    k_gru<true><<<256, 256, 0, stream>>>(gi, resets, h0, bn, WhT, hseq, flags, (float*)d_out);
  } else {
    k_gemm_gi<false><<<3072, 256, 0, stream>>>(xb, WiT, bi, gi);
    k_gru<false><<<256, 256, 0, stream>>>(gi, resets, h0, bn, WhT, hseq, flags, (float*)d_out);
  }
}

// Round 10
// 1281.910 us; speedup vs baseline: 2.1315x; 1.2067x over previous
//
#include <hip/hip_runtime.h>
#include <hip/hip_bf16.h>
#include <cstdint>

// GRU scan: T=256, B=64, H=1024.
// gi = x@Wi + bi precomputed with one bf16 MFMA GEMM; then a persistent
// 256-WG x 256-thread kernel walks 256 sequential steps.
// Protocol: sentinel-in-data (round-5, best measured), upgraded:
//  - canary covers ALL 16 producers of each wave's K-chunk (16 prod x 4 rows)
//  - epilogue/publish/ys/prefetch fully distributed (no wave-0 serial tail);
//    publish is per-wave (wave-local LDS transpose, lanes 0-15 of each wave)
// h_t goes to a fresh slot of hseq[257][64][1024] bf16 (sentinel 0xFF words,
// -NaN bf16, unproducible by finite GRU arithmetic). No flags, no ACK drain.

#define TT 256
#define BB 64
#define HH 1024
#define H3 3072

typedef __attribute__((ext_vector_type(8))) short s16x8;
typedef __attribute__((ext_vector_type(4))) float f32x4;
typedef __attribute__((ext_vector_type(4))) unsigned int u32x4;
typedef unsigned long long ull;

__device__ __forceinline__ float fast_sigmoid(float x) {
  float e = __expf(-fabsf(x));
  float s = 1.0f / (1.0f + e);
  return x >= 0.0f ? s : 1.0f - s;
}
__device__ __forceinline__ float fast_tanh(float x) {
  float e = __expf(-2.0f * fabsf(x));
  float t = (1.0f - e) / (1.0f + e);
  return x >= 0.0f ? t : -t;
}
__device__ __forceinline__ f32x4 mfma16(s16x8 a, s16x8 b, f32x4 c) {
  return __builtin_amdgcn_mfma_f32_16x16x32_bf16(a, b, c, 0, 0, 0);
}

#define LD8(p) __hip_atomic_load((p), __ATOMIC_RELAXED, __HIP_MEMORY_SCOPE_AGENT)
#define ST8(p, v) __hip_atomic_store((p), (v), __ATOMIC_RELAXED, __HIP_MEMORY_SCOPE_AGENT)

// ---------------- setup kernels ----------------

__global__ void k_cvt_x(const float* __restrict__ x, __hip_bfloat16* __restrict__ xb, int n) {
  int i = (blockIdx.x * blockDim.x + threadIdx.x) * 4;
  if (i + 3 < n) {
    float4 v = *reinterpret_cast<const float4*>(x + i);
    xb[i + 0] = __float2bfloat16(v.x);
    xb[i + 1] = __float2bfloat16(v.y);
    xb[i + 2] = __float2bfloat16(v.z);
    xb[i + 3] = __float2bfloat16(v.w);
  }
}

// W [1024][3072] f32 -> WT [3072][1024] bf16
__global__ void k_transpose_w(const float* __restrict__ W, __hip_bfloat16* __restrict__ WT) {
  __shared__ float tile[32][33];
  int c0 = blockIdx.x * 32, r0 = blockIdx.y * 32;
  int tx = threadIdx.x & 31, ty = threadIdx.x >> 5;  // 256 threads: 32x8
#pragma unroll
  for (int i = 0; i < 32; i += 8)
    tile[ty + i][tx] = W[(size_t)(r0 + ty + i) * H3 + c0 + tx];
  __syncthreads();
#pragma unroll
  for (int i = 0; i < 32; i += 8)
    WT[(size_t)(c0 + ty + i) * HH + r0 + tx] = __float2bfloat16(tile[tx][ty + i]);
}

// ---------------- gi = x @ Wi + bi  (bf16 MFMA, 128x128 tile, BK=32) ----------------

template <bool GIF32>
__global__ __launch_bounds__(256, 2) void k_gemm_gi(
    const __hip_bfloat16* __restrict__ A,   // [16384][1024] x bf16
    const __hip_bfloat16* __restrict__ Bt,  // [3072][1024]  Wi^T bf16
    const float* __restrict__ bi,           // [3072]
    void* __restrict__ gi)                  // [16384][3072] f32 or bf16
{
  __shared__ __align__(16) __hip_bfloat16 As[128 * 32];
  __shared__ __align__(16) __hip_bfloat16 Bs[128 * 32];
  const int bid = blockIdx.x;
  const int mt = bid / 24, nt = bid % 24;
  const int m0 = mt * 128, n0 = nt * 128;
  const int tid = threadIdx.x, lane = tid & 63, w = tid >> 6;
  const int wm = w & 1, wn = w >> 1;

  f32x4 acc[4][4];
#pragma unroll
  for (int ai = 0; ai < 4; ++ai)
#pragma unroll
    for (int bj = 0; bj < 4; ++bj) acc[ai][bj] = (f32x4){0.f, 0.f, 0.f, 0.f};

  for (int k0 = 0; k0 < HH; k0 += 32) {
#pragma unroll
    for (int i = 0; i < 2; ++i) {
      const int c = w + i * 4;          // 1KB chunk id, wave-uniform
      const int idx = c * 64 + lane;    // 16B unit id
      const int row = idx >> 2, slot = idx & 3;
      __builtin_amdgcn_global_load_lds(
          (const __attribute__((address_space(1))) void*)(A + (size_t)(m0 + row) * HH + k0 + slot * 8),
          (__attribute__((address_space(3))) void*)(As + c * 512), 16, 0, 0);
      __builtin_amdgcn_global_load_lds(
          (const __attribute__((address_space(1))) void*)(Bt + (size_t)(n0 + row) * HH + k0 + slot * 8),
          (__attribute__((address_space(3))) void*)(Bs + c * 512), 16, 0, 0);
    }
    __syncthreads();
    s16x8 af[4], bf[4];
#pragma unroll
    for (int ai = 0; ai < 4; ++ai) {
      int r = wm * 64 + ai * 16 + (lane & 15);
      af[ai] = *reinterpret_cast<const s16x8*>(As + r * 32 + (lane >> 4) * 8);
    }
#pragma unroll
    for (int bj = 0; bj < 4; ++bj) {
      int r = wn * 64 + bj * 16 + (lane & 15);
      bf[bj] = *reinterpret_cast<const s16x8*>(Bs + r * 32 + (lane >> 4) * 8);
    }
#pragma unroll
    for (int ai = 0; ai < 4; ++ai)
#pragma unroll
      for (int bj = 0; bj < 4; ++bj) acc[ai][bj] = mfma16(af[ai], bf[bj], acc[ai][bj]);
    __syncthreads();
  }

#pragma unroll
  for (int ai = 0; ai < 4; ++ai) {
#pragma unroll
    for (int reg = 0; reg < 4; ++reg) {
      const size_t row = (size_t)m0 + wm * 64 + ai * 16 + (lane >> 4) * 4 + reg;
#pragma unroll
      for (int bj = 0; bj < 4; ++bj) {
        const int col = n0 + wn * 64 + bj * 16 + (lane & 15);
        float v = acc[ai][bj][reg] + bi[col];
        if (GIF32)
          reinterpret_cast<float*>(gi)[row * H3 + col] = v;
        else
          reinterpret_cast<__hip_bfloat16*>(gi)[row * H3 + col] = __float2bfloat16(v);
      }
    }
  }
}

// ---------------- persistent step kernel ----------------

// 256 WGs x 256 threads (4 waves). 4 groups (16 batches) x 64 WGs (16 j-cols).
// Wh^T slice (48 rows x 1024 k, 96 KiB) LDS-resident with XOR swizzle.
// Wave w owns K-chunk w (k in [256w,256w+256) = producers [16w,16w+16)).
// Epilogue: thread tid owns cell (b = bg0 + tid>>4, j = j0 + (tid&15)).
template <bool GIF32>
__global__ __launch_bounds__(256, 1) void k_gru(
    const void* __restrict__ gi_,
    const int* __restrict__ resets,   // [256][64]
    const float* __restrict__ h0,     // [64][1024]
    const float* __restrict__ bn,     // [1024]
    const __hip_bfloat16* __restrict__ WhT,  // [3072][1024]
    __hip_bfloat16* hseq,                    // [257][64][1024] sentinel-filled
    float* __restrict__ out)                 // [64*1024 hfinal | 256*64*1024 ys]
{
  __shared__ __align__(16) __hip_bfloat16 Bsh[48 * 1024];  // 96 KiB
  __shared__ __align__(16) f32x4 part[2][4][3][64];        // 24 KiB partials
  __shared__ __align__(8) __hip_bfloat16 hsh[16][16];      // 512 B transpose
  const int tid = threadIdx.x;
  const int wave = tid >> 6, lane = tid & 63;
  const int wg = blockIdx.x;
  const int g = (wg & 7) >> 1;                // XCD-pair -> group (perf heuristic only)
  const int s = ((wg >> 3) << 1) | (wg & 1);  // 0..63 within group
  const int bg0 = g * 16, j0 = s * 16;

  // stage Wh^T slice into LDS, XOR-swizzled: data(row, slot16B) at byte
  // row*2048 + ((slot*16) ^ ((row&7)<<4))
  for (int cch = tid; cch < 48 * 128; cch += 256) {
    const int row = cch >> 7, slot = cch & 127;
    const int gate = row >> 4, jj = row & 15;
    u32x4 v = *reinterpret_cast<const u32x4*>(WhT + (size_t)(gate * HH + j0 + jj) * HH + slot * 8);
    const int byte = row * 2048 + ((slot * 16) ^ ((row & 7) << 4));
    *reinterpret_cast<u32x4*>(reinterpret_cast<char*>(Bsh) + byte) = v;
  }

  // ---- per-thread epilogue cell: (b, j) ----
  const int bl = tid >> 4;   // 0..15, wave-aligned (bl>>2 == wave)
  const int jl = tid & 15;
  const int b = bg0 + bl, j = j0 + jl;
  const float bnj = bn[j];
  float hp = h0[(size_t)b * HH + j];
  int rstE;
  float giR, giZ, giN;
  {
    rstE = resets[b];
    if (GIF32) {
      const float* grow = reinterpret_cast<const float*>(gi_) + (size_t)b * H3;
      giR = grow[j]; giZ = grow[HH + j]; giN = grow[2 * HH + j];
    } else {
      const __hip_bfloat16* grow = reinterpret_cast<const __hip_bfloat16*>(gi_) + (size_t)b * H3;
      giR = __bfloat162float(grow[j]);
      giZ = __bfloat162float(grow[HH + j]);
      giN = __bfloat162float(grow[2 * HH + j]);
    }
  }

  // publish slot 0 (= h_{-1}): per-wave LDS transpose -> 8B agent stores
  hsh[bl][jl] = __float2bfloat16(hp);
  __syncthreads();  // also covers Bsh staging
  if (lane < 16) {
    const int prow = wave * 4 + (lane >> 2), pq = (lane & 3) * 4;
    ull pv = *reinterpret_cast<const ull*>(&hsh[prow][pq]);
    ST8(reinterpret_cast<ull*>(hseq + (size_t)g * 16384 + prow * HH + j0 + pq), pv);
  }

  // ---- consumer geometry (all 64 lanes of each wave) ----
  const int al = lane & 15;           // A-fragment batch row (group-local)
  const int koff = (lane >> 4) * 8;   // A-fragment k sub-offset (elements)
  const char* bbase = reinterpret_cast<const char*>(Bsh);
  const int xsw = (jl & 7) << 4;
  const int rb0 = jl * 2048, rb1 = (16 + jl) * 2048, rb2 = (32 + jl) * 2048;
  // canary: lane l covers producer (l&15) of this chunk at sampled row (l>>4)*4+1
  const int cprod = lane & 15, crow = (lane >> 4) * 4 + 1;

  for (int t = 0; t < TT; ++t) {
    const int rstA = resets[t * BB + bg0 + al];  // hidden under the spin
    const __hip_bfloat16* rd = hseq + (size_t)t * 65536 + g * 16384;

    // canary spin: all 16 producers of my chunk, 4 sampled rows
    {
      const ull* cp = reinterpret_cast<const ull*>(rd + crow * HH + wave * 256 + cprod * 16 + 8);
      int gq = 0;
      ull c;
      do {
        c = LD8(cp);
      } while (__any((int)(c == ~0ull)) && ++gq < (1 << 20));
    }

    // full chunk load + verify (retries rare: canary covers all producers)
    const ull* ch = reinterpret_cast<const ull*>(rd + al * HH + koff) + wave * 64;
    ull w[16];
#pragma unroll
    for (int i = 0; i < 8; ++i) {
      w[2 * i + 0] = LD8(ch + i * 8 + 0);
      w[2 * i + 1] = LD8(ch + i * 8 + 1);
    }
    {
      int gq = 0;
      for (;;) {
        unsigned bad = 0;
#pragma unroll
        for (int i = 0; i < 16; ++i) bad |= (unsigned)(w[i] == ~0ull);
        if (!__any((int)bad) || ++gq >= (1 << 18)) break;
#pragma unroll
        for (int i = 0; i < 8; ++i) {
          w[2 * i + 0] = LD8(ch + i * 8 + 0);
          w[2 * i + 1] = LD8(ch + i * 8 + 1);
        }
      }
    }

    // 24 partial MFMAs for this wave's K-range
    const ull amask = rstA ? 0ull : ~0ull;
    f32x4 aR = {0.f, 0.f, 0.f, 0.f}, aZ = {0.f, 0.f, 0.f, 0.f}, aN = {0.f, 0.f, 0.f, 0.f};
#pragma unroll
    for (int i = 0; i < 8; ++i) {
      const int kk = wave * 8 + i;
      union { ull q[2]; s16x8 v; } u;
      u.q[0] = w[2 * i + 0] & amask;
      u.q[1] = w[2 * i + 1] & amask;
      const int kb = kk * 64 + (lane >> 4) * 16;
      s16x8 b0 = *reinterpret_cast<const s16x8*>(bbase + rb0 + (kb ^ xsw));
      s16x8 b1 = *reinterpret_cast<const s16x8*>(bbase + rb1 + (kb ^ xsw));
      s16x8 b2 = *reinterpret_cast<const s16x8*>(bbase + rb2 + (kb ^ xsw));
      aR = mfma16(u.v, b0, aR);
      aZ = mfma16(u.v, b1, aZ);
      aN = mfma16(u.v, b2, aN);
    }

    const int p = t & 1;
    part[p][wave][0][lane] = aR;
    part[p][wave][1][lane] = aZ;
    part[p][wave][2][lane] = aN;
    __syncthreads();  // partials visible (parity double-buffer -> one barrier)

    // ---- distributed epilogue: each thread its (b,j) cell ----
    const int li = ((bl >> 2) << 4) | jl, el = bl & 3;
    float sR = part[p][0][0][li][el], sZ = part[p][0][1][li][el], sN = part[p][0][2][li][el];
#pragma unroll
    for (int ww = 1; ww < 4; ++ww) {
      sR += part[p][ww][0][li][el];
      sZ += part[p][ww][1][li][el];
      sN += part[p][ww][2][li][el];
    }
    const float hprev = rstE ? 0.f : hp;
    const float rg = fast_sigmoid(giR + sR);
    const float zg = fast_sigmoid(giZ + sZ);
    const float ng = fast_tanh(giN + rg * (sN + bnj));
    const float hnew = (1.0f - zg) * ng + zg * hprev;
    hp = hnew;

    // publish h_t to slot t+1: per-wave LDS transpose (wave-local rows),
    // lanes 0-15 of EACH wave store 8B -> 4-way parallel publish, no barrier
    hsh[bl][jl] = __float2bfloat16(hnew);
    if (lane < 16) {
      const int prow = wave * 4 + (lane >> 2), pq = (lane & 3) * 4;
      ull pv = *reinterpret_cast<const ull*>(&hsh[prow][pq]);
      ST8(reinterpret_cast<ull*>(hseq + (size_t)(t + 1) * 65536 + g * 16384 + prow * HH + j0 + pq),
          pv);
    }

    // ys write (off the inter-WG critical path)
    __builtin_nontemporal_store(hnew, out + 65536 + (size_t)t * 65536 + (size_t)b * HH + j);

    // prefetch next step's gi / reset (consumed after next canary)
    const int tn = (t + 1 < TT) ? t + 1 : t;
    rstE = resets[tn * BB + b];
    if (GIF32) {
      const float* grow = reinterpret_cast<const float*>(gi_) + (size_t)(tn * BB + b) * H3;
      giR = grow[j]; giZ = grow[HH + j]; giN = grow[2 * HH + j];
    } else {
      const __hip_bfloat16* grow =
          reinterpret_cast<const __hip_bfloat16*>(gi_) + (size_t)(tn * BB + b) * H3;
      giR = __bfloat162float(grow[j]);
      giZ = __bfloat162float(grow[HH + j]);
      giN = __bfloat162float(grow[2 * HH + j]);
    }
  }

  out[(size_t)b * HH + j] = hp;
}

// ---------------- launch ----------------

extern "C" void kernel_launch(void* const* d_in, const int* in_sizes, int n_in,
                              void* d_out, int out_size, void* d_ws, size_t ws_size,
                              hipStream_t stream) {
  const float* x      = (const float*)d_in[0];  // [256,64,1024]
  const int* resets   = (const int*)d_in[1];    // [256,64]
  const float* h0     = (const float*)d_in[2];  // [64,1024]
  const float* Wi     = (const float*)d_in[3];  // [1024,3072]
  const float* bi     = (const float*)d_in[4];  // [3072]
  const float* Wh     = (const float*)d_in[5];  // [1024,3072]
  const float* bn     = (const float*)d_in[6];  // [1024]
  (void)in_sizes; (void)n_in; (void)out_size;

  char* ws = (char*)d_ws;
  // region0: xb [16384][1024] bf16 (33,554,432 B), dead after gemm, then
  //          reused as hseq [257][64][1024] bf16 (33,685,504 B)
  __hip_bfloat16* xb   = (__hip_bfloat16*)(ws);
  __hip_bfloat16* hseq = (__hip_bfloat16*)(ws);
  __hip_bfloat16* WiT  = (__hip_bfloat16*)(ws + 33685504);  // 6,291,456 B
  __hip_bfloat16* WhT  = (__hip_bfloat16*)(ws + 39976960);  // 6,291,456 B
  void* gi             = (void*)(ws + 46268416);

  const bool gif32 = ws_size >= 46268416ull + (size_t)16384 * 3072 * 4;

  k_cvt_x<<<16384, 256, 0, stream>>>(x, xb, TT * BB * HH);
  k_transpose_w<<<dim3(96, 32), 256, 0, stream>>>(Wi, WiT);
  k_transpose_w<<<dim3(96, 32), 256, 0, stream>>>(Wh, WhT);
  if (gif32) {
    k_gemm_gi<true><<<3072, 256, 0, stream>>>(xb, WiT, bi, gi);
    // xb dead; sentinel-fill hseq (0xFF = -NaN bf16 words)
    hipMemsetAsync(hseq, 0xFF, 33685504, stream);
    k_gru<true><<<256, 256, 0, stream>>>(gi, resets, h0, bn, WhT, hseq, (float*)d_out);
  } else {
    k_gemm_gi<false><<<3072, 256, 0, stream>>>(xb, WiT, bi, gi);
    hipMemsetAsync(hseq, 0xFF, 33685504, stream);
    k_gru<false><<<256, 256, 0, stream>>>(gi, resets, h0, bn, WhT, hseq, (float*)d_out);
  }
}